// Round 8
// baseline (166.081 us; speedup 1.0000x reference)
//
#include <hip/hip_runtime.h>

// PersonalizedPageRankGraphAttentionLayer — MI355X gfx950, round 8
// vs round 7:
//  (1) pgemm rewritten: single-wave 64x64 blocks (64 threads), acc[4][4],
//      16 ds_read_b128 + 32 MFMA per 64-K tile (reads/MFMA 0.5 vs 1.0) --
//      the round-7 design was LDS-issue bound (4096 b128/CU ~ 20.5us).
//      Single wave => NO barriers; pipelining via counted s_waitcnt vmcnt(16)
//      (16 in-flight global_load_lds of the next tile) + sched_barrier.
//      Accumulation order per output element unchanged -> absmax should stay
//      bit-identical (0.0429688).
//  (2) Q1t dropped: G3 computes T = E@M + E (EPI2, Bt=Mt) instead of E@Q1.
//      mbuild writes only M, Mt.

typedef unsigned short u16;
typedef float  f32x4  __attribute__((ext_vector_type(4)));
typedef short  s16x8  __attribute__((ext_vector_type(8)));
typedef __bf16 bf16x8 __attribute__((ext_vector_type(8)));

#define NN 2048

__device__ __forceinline__ u16 f2bf(float f) {
    unsigned u = __float_as_uint(f);
    return (u16)((u + 0x7FFFu + ((u >> 16) & 1u)) >> 16);  // RNE
}
__device__ __forceinline__ float bf2f(u16 v) {
    return __uint_as_float(((unsigned)v) << 16);           // exact
}

// ---------------- init ----------------
__global__ void deg_kernel(const float* __restrict__ adj, float* __restrict__ deg,
                           float* __restrict__ invdeg) {
    __shared__ float red[8];
    const int row = blockIdx.x;
    const float* ar = adj + (size_t)row * NN;
    float s = 0.f;
    for (int j = threadIdx.x; j < NN; j += 256) s += ar[j];
    #pragma unroll
    for (int o = 32; o; o >>= 1) s += __shfl_down(s, o);
    if ((threadIdx.x & 63) == 0) red[threadIdx.x >> 6] = s;
    __syncthreads();
    if (threadIdx.x == 0) {
        float t = red[0] + red[1] + red[2] + red[3]; // integer-valued -> exact
        deg[row] = t; invdeg[row] = 1.0f / t;
    }
}

// Build M (bf16) and Mt (bf16 transposed) in one pass.
__global__ void mbuild_kernel(const float* __restrict__ adj, const float* __restrict__ invdeg,
                              u16* __restrict__ M, u16* __restrict__ Mt) {
    __shared__ float tile[32][33];
    const int bx = blockIdx.x * 32, by = blockIdx.y * 32;
    const int x = threadIdx.x, y0 = threadIdx.y;
    #pragma unroll
    for (int k = 0; k < 4; k++) {
        const int y = y0 + k * 8;
        const int row = by + y, col = bx + x;
        const float v = 0.75f * invdeg[row] * adj[(size_t)row * NN + col];
        tile[y][x] = v;
        M[(size_t)row * NN + col] = f2bf(v);
    }
    __syncthreads();
    #pragma unroll
    for (int k = 0; k < 4; k++) {
        const int y = y0 + k * 8;
        Mt[(size_t)(bx + y) * NN + by + x] = f2bf(tile[x][y]);
    }
}

__global__ void f32_to_bf16_kernel(const float* __restrict__ in, u16* __restrict__ out, int n4) {
    int i = blockIdx.x * blockDim.x + threadIdx.x;
    if (i < n4) {
        f32x4 v = ((const f32x4*)in)[i];
        uint2 o;
        o.x = (unsigned)f2bf(v[0]) | ((unsigned)f2bf(v[1]) << 16);
        o.y = (unsigned)f2bf(v[2]) | ((unsigned)f2bf(v[3]) << 16);
        ((uint2*)out)[i] = o;
    }
}

// out[c][r] = bf16(in[r][c])
__global__ void transpose_f32_bf16(const float* __restrict__ in, u16* __restrict__ out,
                                   int rows, int cols) {
    __shared__ float tile[32][33];
    const int bx = blockIdx.x * 32, by = blockIdx.y * 32;
    const int x = threadIdx.x, y0 = threadIdx.y;
    #pragma unroll
    for (int k = 0; k < 4; k++) {
        int y = y0 + k * 8;
        tile[y][x] = in[(size_t)(by + y) * cols + bx + x];
    }
    __syncthreads();
    #pragma unroll
    for (int k = 0; k < 4; k++) {
        int y = y0 + k * 8;
        out[(size_t)(bx + y) * rows + by + x] = f2bf(tile[x][y]);
    }
}

// ---------------- HW = h @ W (64x64 tiles, grid 4x32) + fused h1/h2 partials ----
__global__ __launch_bounds__(256, 4)
void gemm64f_kernel(const u16* __restrict__ A, const u16* __restrict__ Bt,
                    float* __restrict__ C, const float* __restrict__ av,
                    float* __restrict__ h1part, float* __restrict__ h2part,
                    const int N, const int K) {
    __shared__ __align__(16) u16 As[2][64 * 64];
    __shared__ __align__(16) u16 Bs[2][64 * 64];
    __shared__ float hred[64][2][2];   // [local row][col-half][h1/h2]
    const int tid = threadIdx.x, lane = tid & 63, wid = tid >> 6;
    const int trow = blockIdx.y * 64, tcol = blockIdx.x * 64;
    const int wrow = (wid >> 1) * 32, wcol = (wid & 1) * 32;
    const int lrow = lane & 15, lq = lane >> 4;
    const int srow0 = lane >> 3;
    const int g_swz = (lane & 7) ^ (lane >> 3);

    auto stage = [&](int k0, int buf) {
        #pragma unroll
        for (int j = 0; j < 2; j++) {
            const int row = wid * 16 + j * 8 + srow0;
            const u16* ga = A  + (size_t)(trow + row) * K + k0 + g_swz * 8;
            const u16* gb = Bt + (size_t)(tcol + row) * K + k0 + g_swz * 8;
            u16* la = &As[buf][(wid * 128 + j * 64) * 8];
            u16* lb = &Bs[buf][(wid * 128 + j * 64) * 8];
            __builtin_amdgcn_global_load_lds(
                (const __attribute__((address_space(1))) unsigned int*)ga,
                (__attribute__((address_space(3))) unsigned int*)la, 16, 0, 0);
            __builtin_amdgcn_global_load_lds(
                (const __attribute__((address_space(1))) unsigned int*)gb,
                (__attribute__((address_space(3))) unsigned int*)lb, 16, 0, 0);
        }
    };

    f32x4 acc[2][2] = {};
    stage(0, 0);
    __syncthreads();
    const int nks = K / 64;
    for (int ks = 0; ks < nks; ks++) {
        const int cur = ks & 1, nxt = cur ^ 1;
        if (ks < nks - 1) stage((ks + 1) * 64, nxt);
        bf16x8 af[2][2], bfv[2][2];
        #pragma unroll
        for (int kk = 0; kk < 2; kk++) {
            const int gsz = ((kk * 4 + lq) ^ (lrow & 7)) * 8;
            #pragma unroll
            for (int m = 0; m < 2; m++) {
                af[m][kk]  = *(const bf16x8*)&As[cur][(wrow + m * 16 + lrow) * 64 + gsz];
                bfv[m][kk] = *(const bf16x8*)&Bs[cur][(wcol + m * 16 + lrow) * 64 + gsz];
            }
        }
        #pragma unroll
        for (int kk = 0; kk < 2; kk++)
            #pragma unroll
            for (int m = 0; m < 2; m++)
                #pragma unroll
                for (int n = 0; n < 2; n++)
                    acc[m][n] = __builtin_amdgcn_mfma_f32_16x16x32_bf16(
                        af[m][kk], bfv[n][kk], acc[m][n], 0, 0, 0);
        __syncthreads();
    }
    const int crow0 = trow + wrow + lq * 4;
    const int ccol0 = tcol + wcol + lrow;
    float av1[2], av2[2];
    #pragma unroll
    for (int n = 0; n < 2; n++) {
        av1[n] = av[ccol0 + n * 16];
        av2[n] = av[256 + ccol0 + n * 16];
    }
    #pragma unroll
    for (int m = 0; m < 2; m++) {
        #pragma unroll
        for (int r = 0; r < 4; r++) {
            float s1 = 0.f, s2 = 0.f;
            #pragma unroll
            for (int n = 0; n < 2; n++) {
                const float v = acc[m][n][r];
                C[(size_t)(crow0 + m * 16 + r) * N + ccol0 + n * 16] = v;
                s1 += v * av1[n];
                s2 += v * av2[n];
            }
            #pragma unroll
            for (int o = 1; o < 16; o <<= 1) {
                s1 += __shfl_xor(s1, o);
                s2 += __shfl_xor(s2, o);
            }
            if (lrow == 0) {
                const int rl = wrow + lq * 4 + m * 16 + r;
                hred[rl][wid & 1][0] = s1;
                hred[rl][wid & 1][1] = s2;
            }
        }
    }
    __syncthreads();
    if (tid < 64) {
        h1part[(size_t)blockIdx.x * NN + trow + tid] = hred[tid][0][0] + hred[tid][1][0];
        h2part[(size_t)blockIdx.x * NN + trow + tid] = hred[tid][0][1] + hred[tid][1][1];
    }
}

// ---------------- power-series GEMM v2: single-wave 64x64, C = A @ Bt^T ----------
// EPI 1: C = acc, auxWt^T = acc       EPI 2: C = acc + aux1
// EPI 3: C = acc + aux1 + (row==col)
// 64 threads (1 wave), acc[4][4], no barriers; counted vmcnt pipelining.
template <int EPI>
__global__ __launch_bounds__(64, 2)
void pgemm_kernel(const u16* __restrict__ A, const u16* __restrict__ Bt,
                  u16* __restrict__ C, u16* __restrict__ auxWt,
                  const u16* __restrict__ aux1) {
    __shared__ __align__(16) u16 As[2][64 * 64];
    __shared__ __align__(16) u16 Bs[2][64 * 64];
    const int lane = threadIdx.x;              // 0..63
    int bid = blockIdx.x;
    bid = (bid & 7) * 128 + (bid >> 3);        // XCD -> contiguous 128-tile chunk
    const int by = bid >> 5, bx = bid & 31;
    const int trow = by * 64, tcol = bx * 64;
    const int lrow = lane & 15, lq = lane >> 4;
    const int srow0 = lane >> 3;
    const int g_swz = (lane & 7) ^ (lane >> 3);

    // Stage one 64x64 bf16 tile per matrix: 8 global_load_lds(16B) each.
    // LDS granule (row, g') holds logical k-granule g = g' ^ (row&7).
    auto stage = [&](int k0, int buf) {
        #pragma unroll
        for (int j = 0; j < 8; j++) {
            const int row = j * 8 + srow0;
            const u16* ga = A  + (size_t)(trow + row) * NN + k0 + g_swz * 8;
            const u16* gb = Bt + (size_t)(tcol + row) * NN + k0 + g_swz * 8;
            u16* la = &As[buf][j * 512];       // wave-uniform base; lane -> +16B*lane
            u16* lb = &Bs[buf][j * 512];
            __builtin_amdgcn_global_load_lds(
                (const __attribute__((address_space(1))) unsigned int*)ga,
                (__attribute__((address_space(3))) unsigned int*)la, 16, 0, 0);
            __builtin_amdgcn_global_load_lds(
                (const __attribute__((address_space(1))) unsigned int*)gb,
                (__attribute__((address_space(3))) unsigned int*)lb, 16, 0, 0);
        }
    };

    f32x4 acc[4][4] = {};
    stage(0, 0);

    for (int ks = 0; ks < NN / 64; ks++) {
        const int cur = ks & 1;
        if (ks < NN / 64 - 1) {
            stage((ks + 1) * 64, cur ^ 1);     // 16 loads in flight
            asm volatile("s_waitcnt vmcnt(16)" ::: "memory");  // tile ks ready
        } else {
            asm volatile("s_waitcnt vmcnt(0)" ::: "memory");
        }
        __builtin_amdgcn_sched_barrier(0);
        #pragma unroll
        for (int kk = 0; kk < 2; kk++) {
            const int gsz = ((kk * 4 + lq) ^ (lrow & 7)) * 8;
            bf16x8 af[4], bfv[4];
            #pragma unroll
            for (int m = 0; m < 4; m++)
                af[m]  = *(const bf16x8*)&As[cur][(m * 16 + lrow) * 64 + gsz];
            #pragma unroll
            for (int n = 0; n < 4; n++)
                bfv[n] = *(const bf16x8*)&Bs[cur][(n * 16 + lrow) * 64 + gsz];
            #pragma unroll
            for (int m = 0; m < 4; m++)
                #pragma unroll
                for (int n = 0; n < 4; n++)
                    acc[m][n] = __builtin_amdgcn_mfma_f32_16x16x32_bf16(
                        af[m], bfv[n], acc[m][n], 0, 0, 0);
        }
    }

    const int crow0 = trow + lq * 4;
    const int ccol0 = tcol + lrow;
    #pragma unroll
    for (int n = 0; n < 4; n++) {
        const int col = ccol0 + n * 16;
        #pragma unroll
        for (int m = 0; m < 4; m++) {
            #pragma unroll
            for (int r = 0; r < 4; r++) {
                const int row = crow0 + m * 16 + r;
                const size_t off = (size_t)row * NN + col;
                float v = acc[m][n][r];
                if (EPI == 2) v += bf2f(aux1[off]);
                if (EPI == 3) v += bf2f(aux1[off]) + (row == col ? 1.f : 0.f);
                const u16 hv = f2bf(v);
                C[off] = hv;
                if (EPI == 1) auxWt[(size_t)col * NN + row] = hv;
            }
        }
    }
}

// ---------------- wave reduce helpers ----------------
__device__ __forceinline__ int wred_sum_i(int v) {
    #pragma unroll
    for (int o = 32; o; o >>= 1) v += __shfl_down(v, o);
    return __shfl(v, 0);
}
__device__ __forceinline__ float wred_sum_f(float v) {
    #pragma unroll
    for (int o = 32; o; o >>= 1) v += __shfl_down(v, o);
    return __shfl(v, 0);
}
__device__ __forceinline__ float wred_max_f(float v) {
    #pragma unroll
    for (int o = 32; o; o >>= 1) v = fmaxf(v, __shfl_down(v, o));
    return __shfl(v, 0);
}

// ---------------- finalize: wave-per-row; P=0.25*T, top-32, softmax, att@HW ----
__global__ __launch_bounds__(256)
void finalize_kernel(const u16* __restrict__ T, const u16* __restrict__ M,
                     const float* __restrict__ HW,
                     const float* __restrict__ h1p, const float* __restrict__ h2p,
                     const float* __restrict__ degv,
                     const float* __restrict__ a_ppr_p, float* __restrict__ out) {
    __shared__ float Prow[4][NN];     // 32 KB
    __shared__ float nval[4][128];
    __shared__ int   nidx[4][128];
    const int tid = threadIdx.x, lane = tid & 63, wid = tid >> 6;
    const int row = blockIdx.x * 4 + wid;
    float* prow  = Prow[wid];
    float* nval_ = nval[wid];
    int*   nidx_ = nidx[wid];

    // ---- load P row: 32 vals/lane, mirror to LDS ----
    float pv[32];
    const u16* tp = T + (size_t)row * NN;
    #pragma unroll
    for (int i = 0; i < 4; i++) {
        union { s16x8 v; u16 h[8]; } tr;
        tr.v = *(const s16x8*)(tp + i * 512 + lane * 8);
        #pragma unroll
        for (int e = 0; e < 8; e++) {
            const float p = 0.25f * bf2f(tr.h[e]);
            pv[i * 8 + e] = p;
            prow[i * 512 + lane * 8 + e] = p;
        }
    }

    // ---- ordered neighbor compaction from M row (bf16), wave prefix scan ----
    const u16* mr = M + (size_t)row * NN;
    int L = 0;
    #pragma unroll
    for (int i = 0; i < 4; i++) {
        union { s16x8 v; u16 h[8]; } mv;
        mv.v = *(const s16x8*)(mr + i * 512 + lane * 8);
        int b[8]; int cnt = 0;
        #pragma unroll
        for (int e = 0; e < 8; e++) { b[e] = (mv.h[e] != 0); cnt += b[e]; }
        int sc = cnt;
        #pragma unroll
        for (int o = 1; o < 64; o <<= 1) {
            const int t = __shfl_up(sc, o);
            if (lane >= o) sc += t;
        }
        int pos = L + sc - cnt;
        const int j0 = i * 512 + lane * 8;
        #pragma unroll
        for (int e = 0; e < 8; e++) if (b[e] && pos < 128) nidx_[pos++] = j0 + e;
        L += __shfl(sc, 63);
    }
    if (L > 128) L = 128;   // unreachable (max deg ~45)

    // ---- bisection for 32nd-largest of P row (registers + shfl only) ----
    unsigned lo = 0u, hi = 0x40000000u;   // [0, 2.0)
    while (hi - lo > 1u) {
        const unsigned mid = (lo + hi) >> 1;
        const float mf = __uint_as_float(mid);
        int c = 0;
        #pragma unroll
        for (int s = 0; s < 32; s++) c += (pv[s] >= mf);
        c = wred_sum_i(c);
        if (c >= 32) lo = mid; else hi = mid;
    }
    const float cut = __uint_as_float(lo);
    int mg = 0, te = 0;
    #pragma unroll
    for (int s = 0; s < 32; s++) { mg += (pv[s] > cut); te += (pv[s] == cut); }
    mg = wred_sum_i(mg);
    te = wred_sum_i(te);
    const int tsel = 32 - mg;             // ties to take (lowest index first)

    __syncthreads();   // prow + nidx visible across lanes

    // ---- e values for neighbors, wave softmax ----
    const float dgr = degv[row];
    const float apr = a_ppr_p[0];
    const float h1r = h1p[row] + h1p[NN + row] + h1p[2 * NN + row] + h1p[3 * NN + row];
    float mymax = -3.0e38f;
    for (int k = lane; k < L; k += 64) {
        const int j = nidx_[k];
        const float p = prow[j];
        bool sel = p > cut;
        if (!sel && p == cut) {
            if (tsel >= te) sel = true;
            else {
                int rk = 0;
                for (int q = 0; q < j; q++) rk += (prow[q] == cut);
                sel = (rk < tsel);
            }
        }
        const float h2j = h2p[j] + h2p[NN + j] + h2p[2 * NN + j] + h2p[3 * NN + j];
        const float pprv = sel ? p * sqrtf(dgr / degv[j]) : 0.f;
        float e = h1r + h2j + apr * pprv;
        e = (e > 0.f) ? e : 0.2f * e;      // leaky_relu 0.2
        nval_[k] = e;
        mymax = fmaxf(mymax, e);
    }
    const float mx = wred_max_f(mymax);
    float mysum = 0.f;
    for (int k = lane; k < L; k += 64) {
        const float ev = expf(nval_[k] - mx);
        nval_[k] = ev;
        mysum += ev;
    }
    const float inv = 1.f / wred_sum_f(mysum);

    __syncthreads();   // nval visible across lanes

    // ---- out[row, :] = sum_k att_k * HW[j_k, :]; lane owns 4 columns ----
    f32x4 acc = {0.f, 0.f, 0.f, 0.f};
    for (int k = 0; k < L; k++) {
        const float a = nval_[k] * inv;
        const int j = nidx_[k];
        f32x4 hv = *(const f32x4*)(HW + (size_t)j * 256 + lane * 4);
        acc += a * hv;
    }
    *(f32x4*)(out + (size_t)row * 256 + lane * 4) = acc;
}

// ---------------- host ----------------
extern "C" void kernel_launch(void* const* d_in, const int* in_sizes, int n_in,
                              void* d_out, int out_size, void* d_ws, size_t ws_size,
                              hipStream_t stream) {
    const float* h     = (const float*)d_in[0];   // [2048,512]
    const float* adj   = (const float*)d_in[1];   // [2048,2048]
    const float* W     = (const float*)d_in[2];   // [512,256]
    const float* a     = (const float*)d_in[3];   // [512,1]
    const float* a_ppr = (const float*)d_in[4];   // [1,1]
    float* out = (float*)d_out;

    char* ws = (char*)d_ws;
    auto alloc = [&](size_t bytes) { char* p = ws; ws += (bytes + 255) & ~(size_t)255; return p; };
    u16*   B1     = (u16*)  alloc((size_t)NN * NN * 2);   // M (kept for finalize)
    u16*   B2     = (u16*)  alloc((size_t)NN * NN * 2);   // Mt
    u16*   B3     = (u16*)  alloc((size_t)NN * NN * 2);   // E
    u16*   B4     = (u16*)  alloc((size_t)NN * NN * 2);   // M2 -> T
    u16*   B5     = (u16*)  alloc((size_t)NN * NN * 2);   // M2t
    u16*   hb     = (u16*)  alloc((size_t)NN * 512 * 2);
    u16*   Wt     = (u16*)  alloc((size_t)256 * 512 * 2);
    float* HW     = (float*)alloc((size_t)NN * 256 * 4);
    float* deg    = (float*)alloc(NN * 4);
    float* invdeg = (float*)alloc(NN * 4);
    float* h1part = (float*)alloc((size_t)4 * NN * 4);
    float* h2part = (float*)alloc((size_t)4 * NN * 4);

    deg_kernel<<<NN, 256, 0, stream>>>(adj, deg, invdeg);
    mbuild_kernel<<<dim3(64, 64), dim3(32, 8), 0, stream>>>(adj, invdeg, B1, B2);
    f32_to_bf16_kernel<<<1024, 256, 0, stream>>>(h, hb, NN * 512 / 4);
    transpose_f32_bf16<<<dim3(8, 16), dim3(32, 8), 0, stream>>>(W, Wt, 512, 256);
    gemm64f_kernel<<<dim3(4, 32), 256, 0, stream>>>(hb, Wt, HW, a, h1part, h2part, 256, 512);

    // G1: M2 = P(M, Mt); dual-write M2t.        A=B1, Bt=B2 -> C=B4, auxWt=B5
    pgemm_kernel<1><<<1024, 64, 0, stream>>>(B1, B2, B4, B5, nullptr);
    // G2: E = P(M2, M2t) + M2 + I.              A=B4, Bt=B5, aux1=B4 -> C=B3
    pgemm_kernel<3><<<1024, 64, 0, stream>>>(B4, B5, B3, nullptr, B4);
    // G3: T = P(E, Mt) + E = E@M + E.           A=B3, Bt=B2, aux1=B3 -> C=B4
    pgemm_kernel<2><<<1024, 64, 0, stream>>>(B3, B2, B4, nullptr, B3);

    finalize_kernel<<<512, 256, 0, stream>>>(B4, B1, HW, h1part, h2part, deg, a_ppr, out);
}